// Round 8
// baseline (208.724 us; speedup 1.0000x reference)
//
#include <hip/hip_runtime.h>
#include <math.h>

typedef unsigned short ushort_t;
typedef __attribute__((ext_vector_type(8))) short short8;
typedef __attribute__((ext_vector_type(4))) float f32x4;
typedef __attribute__((ext_vector_type(16))) float f32x16;

#define NTILES 12   // 12 tiles x 32 positions = 384 >= 361

// ws ushort layout (bf16 MFMA A-fragments, lane-major 16B blocks):
//   wf1 @0      : 8 outsub32 x 18 kstep16 x 64 lane x 8 = 73728  (K=288: 256 NDI + 16 u + 16 v)
//   wf2 @73728  : 4 outsub32 x 16 kstep16 x 64 lane x 8 = 32768
//   wf3 @106496 : 4 outsub16 x  4 kstep32 x 64 lane x 8 =  8192  (16x16x32 path)
#define WS_W_USHORTS 114688

__device__ inline ushort_t f2bf(float f) {
    unsigned u = __float_as_uint(f);
    return (ushort_t)((u + 0x7FFFu + ((u >> 16) & 1u)) >> 16);
}
__device__ inline unsigned pkbf(float f0, float f1) {
    unsigned a = __float_as_uint(f0) + 0x8000u;
    unsigned b = __float_as_uint(f1) + 0x8000u;
    return __builtin_amdgcn_perm(b, a, 0x07060302u);
}
__device__ inline float leaky(float v) { return fmaxf(v, 0.01f * v); }

__global__ void pack_weights(const float* __restrict__ w1, const float* __restrict__ w2,
                             const float* __restrict__ w3, ushort_t* __restrict__ ws) {
    const int idx = blockIdx.x * 256 + threadIdx.x;
    if (idx >= WS_W_USHORTS) return;
    float val = 0.f;
    if (idx < 73728) {
        // 32x32x16 A-frag: row m = lane&31, k = (lane>>5)*8 + j
        const int j = idx & 7, lane = (idx >> 3) & 63, blk = idx >> 9;
        const int ks = blk % 18, os = blk / 18;
        const int m = lane & 31, hf = lane >> 5;
        const int row = os * 32 + m;
        const int k = ks * 16 + hf * 8 + j;
        if (k < 256) {
            const int i1 = k >> 4, j1 = k & 15;
            val = w1[row * 512 + i1 * 32 + j1 * 2 + 1];      // NDI weight (c=1)
        } else {
            const int sub = k - 256;
            if (sub < 16) {                                  // u coeff: colsum of DI weights
                const int j1 = sub;
                float s = 0.f;
                #pragma unroll
                for (int i1 = 0; i1 < 16; ++i1) s += w1[row * 512 + i1 * 32 + j1 * 2];
                val = s;
            } else {                                         // v coeff: -rowsum of DI weights
                const int i1 = sub - 16;
                float s = 0.f;
                #pragma unroll
                for (int j1 = 0; j1 < 16; ++j1) s += w1[row * 512 + i1 * 32 + j1 * 2];
                val = -s;
            }
        }
    } else if (idx < 106496) {
        const int l = idx - 73728;
        const int j = l & 7, lane = (l >> 3) & 63, blk = l >> 9;
        const int ks = blk & 15, os = blk >> 4;
        const int m = lane & 31, hf = lane >> 5;
        val = w2[(os * 32 + m) * 256 + ks * 16 + hf * 8 + j];
    } else {
        // 16x16x32 A-frag for w3 (unchanged)
        const int l = idx - 106496;
        const int j = l & 7, lane = (l >> 3) & 63, blk = l >> 9;
        const int ks = blk & 3, os = blk >> 2;
        const int m = lane & 15, q = lane >> 4;
        val = w3[(os * 16 + m) * 128 + ks * 32 + q * 8 + j];
    }
    ws[idx] = f2bf(val);
}

// LDS (ushort units). Row swizzle: element (row, oct) at base + row*STR + ((oct ^ sx(row))*8),
// sx(r) = (r + (r>>3)) & 7  -> breaks row-aliasing for 32-row tiles (rows 8 apart differ).
//   ts   @0      32 x 320 (288 ch used) = 10240  } h2s aliases @0, 32x128 = 4096
//   h1s  @10240  32 x 256               =  8192  } wbuf aliases @10240: [w'*4+q][32 pos] f32 = 2048B
//   xp   @18432  308 f32                =   616
// total 19048 ush = 38096 B
template <int NS>
__global__ __launch_bounds__(256, 3) void fused_mfma(
    const float* __restrict__ x, const ushort_t* __restrict__ ws,
    const float* __restrict__ b1, const float* __restrict__ b2,
    const float* __restrict__ b3, const float* __restrict__ b4,
    const float* __restrict__ w4,
    float* __restrict__ partA, float* __restrict__ partS)
{
    __shared__ __align__(16) ushort_t sm[19048];
    ushort_t* const ts   = sm;
    ushort_t* const h2s  = sm;                    // aliases ts
    ushort_t* const h1s  = sm + 10240;
    float*   const wbuf  = (float*)(sm + 10240);  // aliases h1s head
    float*   const xp    = (float*)(sm + 18432);

    constexpr int SH  = (NS == 4) ? 2 : ((NS == 2) ? 1 : 0);
    constexpr int TPS = (NTILES + NS - 1) / NS;
    const int tid = threadIdx.x;
    const int s   = blockIdx.x & (NS - 1);
    const int bb  = blockIdx.x >> SH;
    const int t0  = s * TPS;
    const int t1  = (t0 + TPS < NTILES) ? (t0 + TPS) : NTILES;

    const int wid   = tid >> 6;
    const int lane  = tid & 63;
    const int n     = lane & 31;           // position within tile (32-wide)
    const int half5 = lane >> 5;           // 0/1
    const int sxn   = (n + (n >> 3)) & 7;
    // 16x16 identities for L3 path
    const int n0  = lane & 15;
    const int qi  = lane >> 4;
    const int sxa = (n0 + (n0 >> 3)) & 7;
    const int n0b = n0 + 16;
    const int sxb = (n0b + (n0b >> 3)) & 7;

    for (int jj = tid; jj < 308; jj += 256) {
        float v = 0.f;
        const int src = jj - 2;
        if (src >= 0 && src < 300) v = x[bb * 300 + src];
        xp[jj] = v;
    }

    const short8* wf1 = (const short8*)(ws);
    const short8* wf2 = (const short8*)(ws + 73728);
    const short8* wf3 = (const short8*)(ws + 106496);

    // bias registers as acc-initializers (f32x16 C-layout)
    f32x16 bv1f[2], bv2f;
    #pragma unroll
    for (int jo = 0; jo < 2; ++jo) {
        #pragma unroll
        for (int g = 0; g < 4; ++g) {
            const f32x4 t4 = *(const f32x4*)&b1[(wid * 2 + jo) * 32 + 8 * g + 4 * half5];
            bv1f[jo][4 * g + 0] = t4.x; bv1f[jo][4 * g + 1] = t4.y;
            bv1f[jo][4 * g + 2] = t4.z; bv1f[jo][4 * g + 3] = t4.w;
        }
    }
    #pragma unroll
    for (int g = 0; g < 4; ++g) {
        const f32x4 t4 = *(const f32x4*)&b2[wid * 32 + 8 * g + 4 * half5];
        bv2f[4 * g + 0] = t4.x; bv2f[4 * g + 1] = t4.y;
        bv2f[4 * g + 2] = t4.z; bv2f[4 * g + 3] = t4.w;
    }
    const f32x4 bv3 = *(const f32x4*)&b3[wid * 16 + qi * 4];
    const float b4s = b4[wid];

    f32x16 Afr = {0.f};
    float Ss = 0.f;

    __syncthreads();

    for (int tile = t0; tile < t1; ++tile) {
        const int pos0 = tile * 32;

        // ---- build t tile: thread = (p = tid&31, i1b = tid>>5), i1 in {i1b, i1b+8} ----
        {
            const int p   = tid & 31;
            const int i1b = tid >> 5;
            int posg = pos0 + p; if (posg > 360) posg = 360;
            const int hh = posg / 19;
            const int ww = posg - 19 * hh;
            const int base = p * 320;
            const int sxp  = (p + (p >> 3)) & 7;
            float u[16];
            #pragma unroll
            for (int j1 = 0; j1 < 16; ++j1) u[j1] = xp[j1 * 19 + ww];
            #pragma unroll
            for (int ii = 0; ii < 2; ++ii) {
                const int i1 = i1b + ii * 8;
                const float v = xp[i1 * 19 + hh];
                #pragma unroll
                for (int j1 = 0; j1 < 16; j1 += 2) {
                    const float nd0 = (u[j1] - v)     * __builtin_amdgcn_rcpf(u[j1] + v + 1e-5f);
                    const float nd1 = (u[j1 + 1] - v) * __builtin_amdgcn_rcpf(u[j1 + 1] + v + 1e-5f);
                    const int oct = i1 * 2 + (j1 >> 3);
                    *(unsigned*)&ts[base + ((oct ^ sxp) << 3) + (j1 & 7)] = pkbf(nd0, nd1);
                }
            }
            if (i1b == 0) {  // ext channels: u at 256..271, v at 272..287
                #pragma unroll
                for (int j1 = 0; j1 < 16; j1 += 2) {
                    const int oct = 32 + (j1 >> 3);
                    *(unsigned*)&ts[base + ((oct ^ sxp) << 3) + (j1 & 7)] = pkbf(u[j1], u[j1 + 1]);
                }
                #pragma unroll
                for (int i1 = 0; i1 < 16; i1 += 2) {
                    const float v0 = xp[i1 * 19 + hh];
                    const float v1 = xp[(i1 + 1) * 19 + hh];
                    const int oct = 34 + (i1 >> 3);
                    *(unsigned*)&ts[base + ((oct ^ sxp) << 3) + (i1 & 7)] = pkbf(v0, v1);
                }
            }
        }
        __syncthreads();   // B1: ts ready

        // ---- layer 1: 256 outs, K=288; 32x32x16, wave = 2 outsubs x 1 possub(32) ----
        {
            f32x16 acc[2] = {bv1f[0], bv1f[1]};
            const int tb = n * 320;
            #pragma unroll 6
            for (int ks = 0; ks < 18; ++ks) {
                const int oct = ks * 2 + half5;
                const short8 bbv = *(const short8*)&ts[tb + ((oct ^ sxn) << 3)];
                acc[0] = __builtin_amdgcn_mfma_f32_32x32x16_bf16(
                    wf1[((wid * 2 + 0) * 18 + ks) * 64 + lane], bbv, acc[0], 0, 0, 0);
                acc[1] = __builtin_amdgcn_mfma_f32_32x32x16_bf16(
                    wf1[((wid * 2 + 1) * 18 + ks) * 64 + lane], bbv, acc[1], 0, 0, 0);
            }
            #pragma unroll
            for (int jo = 0; jo < 2; ++jo) {
                const int osb = (wid * 2 + jo) * 32;
                #pragma unroll
                for (int g = 0; g < 4; ++g) {
                    uint2 pk;
                    pk.x = pkbf(leaky(acc[jo][4 * g + 0]), leaky(acc[jo][4 * g + 1]));
                    pk.y = pkbf(leaky(acc[jo][4 * g + 2]), leaky(acc[jo][4 * g + 3]));
                    const int ch0 = osb + 8 * g + 4 * half5;
                    *(uint2*)&h1s[n * 256 + (((ch0 >> 3) ^ sxn) << 3) + (ch0 & 7)] = pk;
                }
            }
        }
        __syncthreads();   // B2: h1s ready; orders L1 ts-reads before L2 h2s(=ts) writes

        // ---- layer 2: 128 outs, K=256; 32x32x16, wave = 1 outsub; h2 kept in f32 regs ----
        f32x16 h2v;
        {
            f32x16 acc = bv2f;
            const int hb = n * 256;
            #pragma unroll 8
            for (int ks = 0; ks < 16; ++ks) {
                const int oct = ks * 2 + half5;
                const short8 bbv = *(const short8*)&h1s[hb + ((oct ^ sxn) << 3)];
                acc = __builtin_amdgcn_mfma_f32_32x32x16_bf16(
                    wf2[(wid * 16 + ks) * 64 + lane], bbv, acc, 0, 0, 0);
            }
            #pragma unroll
            for (int r = 0; r < 16; ++r) h2v[r] = leaky(acc[r]);
            #pragma unroll
            for (int g = 0; g < 4; ++g) {
                uint2 pk;
                pk.x = pkbf(h2v[4 * g + 0], h2v[4 * g + 1]);
                pk.y = pkbf(h2v[4 * g + 2], h2v[4 * g + 3]);
                const int ch0 = wid * 32 + 8 * g + 4 * half5;
                *(uint2*)&h2s[n * 128 + (((ch0 >> 3) ^ sxn) << 3) + (ch0 & 7)] = pk;
            }
        }
        __syncthreads();   // B3: h2s ready

        // ---- layer 3 (16x16x32, 2 possubs) + L4 partial logits in registers ----
        {
            f32x4 acc3[2] = {bv3, bv3};
            const int cb0 = n0 * 128;
            const int cb1 = n0b * 128;
            #pragma unroll
            for (int ks = 0; ks < 4; ++ks) {
                const int oct = ks * 4 + qi;
                const short8 bb0 = *(const short8*)&h2s[cb0 + ((oct ^ sxa) << 3)];
                const short8 bb1 = *(const short8*)&h2s[cb1 + ((oct ^ sxb) << 3)];
                const short8 a = wf3[(wid * 4 + ks) * 64 + lane];
                acc3[0] = __builtin_amdgcn_mfma_f32_16x16x32_bf16(a, bb0, acc3[0], 0, 0, 0);
                acc3[1] = __builtin_amdgcn_mfma_f32_16x16x32_bf16(a, bb1, acc3[1], 0, 0, 0);
            }
            f32x4 w4r[4];
            #pragma unroll
            for (int q = 0; q < 4; ++q) w4r[q] = *(const f32x4*)&w4[q * 64 + wid * 16 + qi * 4];
            #pragma unroll
            for (int ps = 0; ps < 2; ++ps) {
                f32x4 m3 = acc3[ps];
                m3.x = fmaxf(m3.x, 0.f); m3.y = fmaxf(m3.y, 0.f);
                m3.z = fmaxf(m3.z, 0.f); m3.w = fmaxf(m3.w, 0.f);
                float pl[4];
                #pragma unroll
                for (int q = 0; q < 4; ++q)
                    pl[q] = w4r[q].x * m3.x + w4r[q].y * m3.y + w4r[q].z * m3.z + w4r[q].w * m3.w;
                #pragma unroll
                for (int q = 0; q < 4; ++q) {
                    pl[q] += __shfl_xor(pl[q], 16, 64);
                    pl[q] += __shfl_xor(pl[q], 32, 64);
                }
                if (qi == 0) {
                    #pragma unroll
                    for (int q = 0; q < 4; ++q)
                        wbuf[(wid * 4 + q) * 32 + ps * 16 + n0] = pl[q];
                }
            }
        }
        __syncthreads();   // B4: wbuf ready; all h2s reads done -> next build safe

        // ---- accum: one exp per lane (head = wid), 16-wide register FMA ----
        {
            float lg = wbuf[(0 * 4 + wid) * 32 + n] + wbuf[(1 * 4 + wid) * 32 + n]
                     + wbuf[(2 * 4 + wid) * 32 + n] + wbuf[(3 * 4 + wid) * 32 + n] + b4s;
            lg = fmaxf(lg, 0.f);
            const float e = ((pos0 + n) > 360) ? 0.f : __expf(lg);
            #pragma unroll
            for (int r = 0; r < 16; ++r) Afr[r] += e * h2v[r];
            Ss += e;
        }
        // no trailing barrier: next tile's B1 orders accum(all waves) before h1s(=wbuf) rewrite
    }

    // reduce over positions n (within each h-half; halves hold disjoint ch sets)
    #pragma unroll
    for (int bit = 1; bit < 32; bit <<= 1) {
        #pragma unroll
        for (int r = 0; r < 16; ++r) Afr[r] += __shfl_xor(Afr[r], bit, 64);
        Ss += __shfl_xor(Ss, bit, 64);
    }
    if (n == 0) {
        const int pbA = (s * 512 + bb) * 128 + wid * 32 + 4 * half5;
        #pragma unroll
        for (int g = 0; g < 4; ++g) {
            f32x4 o4;
            o4.x = Afr[4 * g + 0]; o4.y = Afr[4 * g + 1];
            o4.z = Afr[4 * g + 2]; o4.w = Afr[4 * g + 3];
            *(f32x4*)&partA[pbA + 8 * g] = o4;
        }
        if (half5 == 0) partS[(s * 512 + bb) * 4 + wid] = Ss;
    }
}

template <int NS>
__global__ void merge_out(const float* __restrict__ partA, const float* __restrict__ partS,
                          float* __restrict__ out) {
    const int idx = blockIdx.x * 256 + threadIdx.x;
    if (idx >= 512 * 128) return;
    const int bb = idx >> 7, ch = idx & 127;
    const int q = ch >> 5;
    float Sf = 0.f, Af = 0.f;
    #pragma unroll
    for (int s = 0; s < NS; ++s) {
        Af += partA[(s * 512 + bb) * 128 + ch];
        Sf += partS[(s * 512 + bb) * 4 + q];
    }
    out[idx] = Af / Sf;
}

// ---------------- f32 scalar fallback (known-correct, ws-free) ----------------
__global__ __launch_bounds__(256, 2) void fallback_fused(
    const float* __restrict__ x,
    const float* __restrict__ w1, const float* __restrict__ b1,
    const float* __restrict__ w2, const float* __restrict__ b2,
    const float* __restrict__ w3, const float* __restrict__ b3,
    const float* __restrict__ w4, const float* __restrict__ b4,
    float* __restrict__ out)
{
    __shared__ float smf[14644];
    float* const xp  = smf;
    float* const ts  = smf + 308;
    float* const h1s = smf + 8500;
    float* const h2s = smf + 12596;
    float* const m3s = ts;
    float* const lgs = ts + 1024;

    const int tid = threadIdx.x;
    const int b   = blockIdx.x;
    for (int j = tid; j < 308; j += 256) {
        float v = 0.f;
        const int src = j - 2;
        if (src >= 0 && src < 300) v = x[b * 300 + src];
        xp[j] = v;
    }
    __syncthreads();
    const int q = tid >> 5, dd = tid & 31;
    float M = -1e30f, S = 0.f, A = 0.f;
    for (int tile = 0; tile < 23; ++tile) {
        const int pos0 = tile * 16;
        {
            const int p = tid & 15, kk0 = tid >> 4;
            const int pos = pos0 + p;
            const bool valid = (pos < 361);
            const int hh = valid ? (pos / 19) : 0;
            const int ww = valid ? (pos - hh * 19) : 0;
            #pragma unroll
            for (int i = 0; i < 16; ++i) {
                const int kk = kk0 + (i << 4);
                const int i1 = kk >> 4, j1 = kk & 15;
                float di = 0.f, ndi = 0.f;
                if (valid) {
                    const float u = xp[j1 * 19 + ww];
                    const float v = xp[i1 * 19 + hh];
                    di = u - v; ndi = di / (u + v + 1e-5f);
                }
                ts[(kk << 5) + p] = di;
                ts[(kk << 5) + 16 + p] = ndi;
            }
        }
        __syncthreads();
        {
            const int o = tid;
            float acc[16];
            const float bias = b1[o];
            #pragma unroll
            for (int p = 0; p < 16; ++p) acc[p] = bias;
            for (int k = 0; k < 512; ++k) {
                const float wv = w1[o * 512 + k];
                #pragma unroll
                for (int p = 0; p < 16; ++p) acc[p] += wv * ts[(k << 4) + p];
            }
            #pragma unroll
            for (int p = 0; p < 16; ++p) h1s[(o << 4) + p] = (acc[p] >= 0.f) ? acc[p] : 0.01f * acc[p];
        }
        __syncthreads();
        {
            const int o2 = tid & 127, pb = (tid >> 7) << 3;
            float acc[8];
            const float bias = b2[o2];
            #pragma unroll
            for (int j = 0; j < 8; ++j) acc[j] = bias;
            for (int k = 0; k < 256; ++k) {
                const float wv = w2[o2 * 256 + k];
                #pragma unroll
                for (int j = 0; j < 8; ++j) acc[j] += wv * h1s[(k << 4) + pb + j];
            }
            #pragma unroll
            for (int j = 0; j < 8; ++j) h2s[(o2 << 4) + pb + j] = (acc[j] >= 0.f) ? acc[j] : 0.01f * acc[j];
        }
        __syncthreads();
        {
            const int o3 = tid & 63, pb = (tid >> 6) << 2;
            float acc[4];
            const float bias = b3[o3];
            #pragma unroll
            for (int j = 0; j < 4; ++j) acc[j] = bias;
            for (int k = 0; k < 128; ++k) {
                const float wv = w3[o3 * 128 + k];
                #pragma unroll
                for (int j = 0; j < 4; ++j) acc[j] += wv * h2s[(k << 4) + pb + j];
            }
            #pragma unroll
            for (int j = 0; j < 4; ++j) m3s[(o3 << 4) + pb + j] = fmaxf(acc[j], 0.f);
        }
        __syncthreads();
        if (tid < 64) {
            const int o4 = tid >> 4, p = tid & 15;
            float a = b4[o4];
            for (int k = 0; k < 64; ++k) a += w4[o4 * 64 + k] * m3s[(k << 4) + p];
            a = fmaxf(a, 0.f);
            if (pos0 + p >= 361) a = -1e30f;
            lgs[(o4 << 4) + p] = a;
        }
        __syncthreads();
        if (tid < 128) {
            float l[16];
            #pragma unroll
            for (int p = 0; p < 16; ++p) l[p] = lgs[(q << 4) + p];
            float tmax = l[0];
            #pragma unroll
            for (int p = 1; p < 16; ++p) tmax = fmaxf(tmax, l[p]);
            const float newM = fmaxf(M, tmax);
            const float alpha = __expf(M - newM);
            float ssum = 0.f, asum = 0.f;
            #pragma unroll
            for (int p = 0; p < 16; ++p) {
                const float e = __expf(l[p] - newM);
                ssum += e;
                asum += e * h2s[(((q << 5) + dd) << 4) + p];
            }
            S = S * alpha + ssum; A = A * alpha + asum; M = newM;
        }
        __syncthreads();
    }
    if (tid < 128) out[(b << 7) + tid] = A / S;
}

extern "C" void kernel_launch(void* const* d_in, const int* in_sizes, int n_in,
                              void* d_out, int out_size, void* d_ws, size_t ws_size,
                              hipStream_t stream) {
    const float* x  = (const float*)d_in[0];
    const float* w1 = (const float*)d_in[1];
    const float* b1 = (const float*)d_in[2];
    const float* w2 = (const float*)d_in[3];
    const float* b2 = (const float*)d_in[4];
    const float* w3 = (const float*)d_in[5];
    const float* b3 = (const float*)d_in[6];
    const float* w4 = (const float*)d_in[7];
    const float* b4 = (const float*)d_in[8];
    float* out = (float*)d_out;

    const size_t wbytes = (size_t)WS_W_USHORTS * sizeof(ushort_t);
    ushort_t* ws = (ushort_t*)d_ws;
    const int packBlocks = (WS_W_USHORTS + 255) / 256;

    const size_t need4 = wbytes + (size_t)4 * 512 * 132 * sizeof(float);
    const size_t need2 = wbytes + (size_t)2 * 512 * 132 * sizeof(float);
    const size_t need1 = wbytes + (size_t)1 * 512 * 132 * sizeof(float);

    if (ws_size >= need4) {
        float* pA = (float*)((char*)d_ws + wbytes);
        float* pS = pA + (size_t)4 * 512 * 128;
        pack_weights<<<packBlocks, 256, 0, stream>>>(w1, w2, w3, ws);
        fused_mfma<4><<<2048, 256, 0, stream>>>(x, ws, b1, b2, b3, b4, w4, pA, pS);
        merge_out<4><<<256, 256, 0, stream>>>(pA, pS, out);
    } else if (ws_size >= need2) {
        float* pA = (float*)((char*)d_ws + wbytes);
        float* pS = pA + (size_t)2 * 512 * 128;
        pack_weights<<<packBlocks, 256, 0, stream>>>(w1, w2, w3, ws);
        fused_mfma<2><<<1024, 256, 0, stream>>>(x, ws, b1, b2, b3, b4, w4, pA, pS);
        merge_out<2><<<256, 256, 0, stream>>>(pA, pS, out);
    } else if (ws_size >= need1) {
        float* pA = (float*)((char*)d_ws + wbytes);
        float* pS = pA + (size_t)1 * 512 * 128;
        pack_weights<<<packBlocks, 256, 0, stream>>>(w1, w2, w3, ws);
        fused_mfma<1><<<512, 256, 0, stream>>>(x, ws, b1, b2, b3, b4, w4, pA, pS);
        merge_out<1><<<256, 256, 0, stream>>>(pA, pS, out);
    } else {
        fallback_fused<<<512, 256, 0, stream>>>(x, w1, b1, w2, b2, w3, b3, w4, b4, out);
    }
}

// Round 9
// 150.381 us; speedup vs baseline: 1.3880x; 1.3880x over previous
//
#include <hip/hip_runtime.h>
#include <math.h>

typedef unsigned short ushort_t;
typedef __attribute__((ext_vector_type(8))) short short8;
typedef __attribute__((ext_vector_type(4))) float f32x4;

#define NTILES 12   // 12 tiles x 32 positions = 384 >= 361

// ws ushort layout (bf16 MFMA A-fragments, lane-major 16B blocks) — 16x16 shapes:
//   wf1 @0      : 16 outsub x 9 kstep x 64 lane x 8 = 73728  (K=288: 256 NDI + 16 u + 16 v)
//   wf2 @73728  :  8 outsub x 8 kstep x 64 lane x 8 = 32768
//   wf3 @106496 :  4 outsub x 4 kstep x 64 lane x 8 =  8192
#define WS_W_USHORTS 114688

__device__ inline ushort_t f2bf(float f) {
    unsigned u = __float_as_uint(f);
    return (ushort_t)((u + 0x7FFFu + ((u >> 16) & 1u)) >> 16);
}
__device__ inline unsigned pkbf(float f0, float f1) {
    unsigned a = __float_as_uint(f0) + 0x8000u;
    unsigned b = __float_as_uint(f1) + 0x8000u;
    return __builtin_amdgcn_perm(b, a, 0x07060302u);
}
__device__ inline float leaky(float v) { return fmaxf(v, 0.01f * v); }

__global__ void pack_weights(const float* __restrict__ w1, const float* __restrict__ w2,
                             const float* __restrict__ w3, ushort_t* __restrict__ ws) {
    const int idx = blockIdx.x * 256 + threadIdx.x;
    if (idx >= WS_W_USHORTS) return;
    float val = 0.f;
    if (idx < 73728) {
        const int j = idx & 7, lane = (idx >> 3) & 63, blk = idx >> 9;
        const int ks = blk % 9, os = blk / 9;
        const int m = lane & 15, q = lane >> 4;
        const int row = os * 16 + m;
        if (ks < 8) {
            const int k = ks * 32 + q * 8 + j;
            const int i1 = k >> 4, j1 = k & 15;
            val = w1[row * 512 + i1 * 32 + j1 * 2 + 1];      // NDI weight (c=1)
        } else {
            const int sub = q * 8 + j;
            if (sub < 16) {                                  // u coeff: colsum of DI weights
                const int j1 = sub;
                float s = 0.f;
                #pragma unroll
                for (int i1 = 0; i1 < 16; ++i1) s += w1[row * 512 + i1 * 32 + j1 * 2];
                val = s;
            } else {                                         // v coeff: -rowsum of DI weights
                const int i1 = sub - 16;
                float s = 0.f;
                #pragma unroll
                for (int j1 = 0; j1 < 16; ++j1) s += w1[row * 512 + i1 * 32 + j1 * 2];
                val = -s;
            }
        }
    } else if (idx < 106496) {
        const int l = idx - 73728;
        const int j = l & 7, lane = (l >> 3) & 63, blk = l >> 9;
        const int ks = blk & 7, os = blk >> 3;
        const int m = lane & 15, q = lane >> 4;
        val = w2[(os * 16 + m) * 256 + ks * 32 + q * 8 + j];
    } else {
        const int l = idx - 106496;
        const int j = l & 7, lane = (l >> 3) & 63, blk = l >> 9;
        const int ks = blk & 3, os = blk >> 2;
        const int m = lane & 15, q = lane >> 4;
        val = w3[(os * 16 + m) * 128 + ks * 32 + q * 8 + j];
    }
    ws[idx] = f2bf(val);
}

// LDS (ushort units), XOR-swizzled: element (row, oct) at base + row*STR + ((oct ^ (row&7))*8)
//   ts   @0      32 x 320 (288 ch used) = 10240  } h2s aliases @0, 32x128 = 4096
//   h1s  @10240  32 x 256               =  8192  } wbuf aliases @10240: [sub*4+q][32 pos] f32 = 2048B
//   xp   @18432  308 f32                =   616
// total 19048 ush = 38096 B -> 4 blocks/CU by LDS; 8 waves/block
template <int NS>
__global__ __launch_bounds__(512, 4) void fused_mfma(
    const float* __restrict__ x, const ushort_t* __restrict__ ws,
    const float* __restrict__ b1, const float* __restrict__ b2,
    const float* __restrict__ b3, const float* __restrict__ b4,
    const float* __restrict__ w4,
    float* __restrict__ partA, float* __restrict__ partS)
{
    __shared__ __align__(16) ushort_t sm[19048];
    ushort_t* const ts   = sm;
    ushort_t* const h2s  = sm;                    // aliases ts
    ushort_t* const h1s  = sm + 10240;
    float*   const wbuf  = (float*)(sm + 10240);  // aliases h1s head
    float*   const xp    = (float*)(sm + 18432);

    constexpr int SH  = (NS == 4) ? 2 : ((NS == 2) ? 1 : 0);
    constexpr int TPS = (NTILES + NS - 1) / NS;
    const int tid = threadIdx.x;
    const int s   = blockIdx.x & (NS - 1);
    const int bb  = blockIdx.x >> SH;
    const int t0  = s * TPS;
    const int t1  = (t0 + TPS < NTILES) ? (t0 + TPS) : NTILES;

    const int wv   = tid >> 6;          // 0..7
    const int lane = tid & 63;
    const int n0   = lane & 15;
    const int qi   = lane >> 4;
    const int sx   = n0 & 7;
    const int row0 = qi * 4;
    const int o3s  = wv & 3;            // L3 outsub
    const int ps3  = wv >> 2;           // L3 possub
    const int qh   = wv >> 1;           // softmax head for this wave's L2 channels

    for (int jj = tid; jj < 308; jj += 512) {
        float v = 0.f;
        const int src = jj - 2;
        if (src >= 0 && src < 300) v = x[bb * 300 + src];
        xp[jj] = v;
    }

    const short8* wf1 = (const short8*)(ws);
    const short8* wf2 = (const short8*)(ws + 73728);
    const short8* wf3 = (const short8*)(ws + 106496);

    // hoisted bias fragments
    f32x4 bv1[2], bv2, bv3;
    #pragma unroll
    for (int jo = 0; jo < 2; ++jo) bv1[jo] = *(const f32x4*)&b1[(wv * 2 + jo) * 16 + row0];
    bv2 = *(const f32x4*)&b2[wv * 16 + row0];
    bv3 = *(const f32x4*)&b3[o3s * 16 + row0];
    const float b4s = b4[qh];

    // softmax accumulators in L2 C-frag layout (wave's 16-ch slice x 2 possubs)
    f32x4 Afr[2] = {{0.f, 0.f, 0.f, 0.f}, {0.f, 0.f, 0.f, 0.f}};
    float Ss = 0.f;

    __syncthreads();

    for (int tile = t0; tile < t1; ++tile) {
        const int pos0 = tile * 32;

        // ---- build t tile: thread = (p = tid&31, i1 = tid>>5 in 0..15) ----
        {
            const int p  = tid & 31;
            const int i1 = tid >> 5;
            int posg = pos0 + p; if (posg > 360) posg = 360;
            const int hh = posg / 19;
            const int ww = posg - 19 * hh;
            const int base = p * 320;
            const int psw  = p & 7;
            const float v = xp[i1 * 19 + hh];
            float u[16];
            #pragma unroll
            for (int j1 = 0; j1 < 16; ++j1) u[j1] = xp[j1 * 19 + ww];
            #pragma unroll
            for (int j1 = 0; j1 < 16; j1 += 2) {
                const float nd0 = (u[j1] - v)     * __builtin_amdgcn_rcpf(u[j1] + v + 1e-5f);
                const float nd1 = (u[j1 + 1] - v) * __builtin_amdgcn_rcpf(u[j1 + 1] + v + 1e-5f);
                const int oct = i1 * 2 + (j1 >> 3);
                *(unsigned*)&ts[base + ((oct ^ psw) << 3) + (j1 & 7)] = pkbf(nd0, nd1);
            }
            if (i1 == 0) {        // u-ext channels 256..271
                #pragma unroll
                for (int j1 = 0; j1 < 16; j1 += 2) {
                    const int oct = 32 + (j1 >> 3);
                    *(unsigned*)&ts[base + ((oct ^ psw) << 3) + (j1 & 7)] = pkbf(u[j1], u[j1 + 1]);
                }
            } else if (i1 == 1) { // v-ext channels 272..287
                #pragma unroll
                for (int i2 = 0; i2 < 16; i2 += 2) {
                    const float v0 = xp[i2 * 19 + hh];
                    const float v1 = xp[(i2 + 1) * 19 + hh];
                    const int oct = 34 + (i2 >> 3);
                    *(unsigned*)&ts[base + ((oct ^ psw) << 3) + (i2 & 7)] = pkbf(v0, v1);
                }
            }
        }
        __syncthreads();   // B1: ts ready

        // ---- layer 1: 256 outs, K=288 (9 ksteps); wave = 2 outsubs x 2 possubs ----
        {
            f32x4 acc[2][2];
            #pragma unroll
            for (int jo = 0; jo < 2; ++jo) { acc[jo][0] = bv1[jo]; acc[jo][1] = bv1[jo]; }
            const int tb0 = n0 * 320;
            const int tb1 = tb0 + 16 * 320;
            const int wbase = wv * 1152 + lane;   // wv*2 outsubs * 9 ksteps * 64
            #pragma unroll 3
            for (int ks = 0; ks < 9; ++ks) {
                const int oct = ks * 4 + qi;
                const short8 bb0 = *(const short8*)&ts[tb0 + ((oct ^ sx) << 3)];
                const short8 bb1 = *(const short8*)&ts[tb1 + ((oct ^ sx) << 3)];
                #pragma unroll
                for (int jo = 0; jo < 2; ++jo) {
                    const short8 a = wf1[wbase + (jo * 9 + ks) * 64];
                    acc[jo][0] = __builtin_amdgcn_mfma_f32_16x16x32_bf16(a, bb0, acc[jo][0], 0, 0, 0);
                    acc[jo][1] = __builtin_amdgcn_mfma_f32_16x16x32_bf16(a, bb1, acc[jo][1], 0, 0, 0);
                }
            }
            #pragma unroll
            for (int jo = 0; jo < 2; ++jo) {
                const int out0 = (wv * 2 + jo) * 16 + row0;
                #pragma unroll
                for (int ps = 0; ps < 2; ++ps) {
                    const f32x4 a4 = acc[jo][ps];
                    uint2 pk;
                    pk.x = pkbf(leaky(a4.x), leaky(a4.y));
                    pk.y = pkbf(leaky(a4.z), leaky(a4.w));
                    *(uint2*)&h1s[(ps * 16 + n0) * 256 + (((out0 >> 3) ^ sx) << 3) + (out0 & 7)] = pk;
                }
            }
        }
        __syncthreads();   // B2: h1s ready; orders L1 ts-reads before L2 h2s(=ts) writes

        // ---- layer 2: 128 outs, K=256; wave = 1 outsub x 2 possubs; h2 kept in f32 regs ----
        f32x4 h2f[2];
        {
            f32x4 acc[2] = {bv2, bv2};
            const int hb0 = n0 * 256;
            const int hb1 = hb0 + 16 * 256;
            #pragma unroll 4
            for (int ks = 0; ks < 8; ++ks) {
                const int oct = ks * 4 + qi;
                const short8 bb0 = *(const short8*)&h1s[hb0 + ((oct ^ sx) << 3)];
                const short8 bb1 = *(const short8*)&h1s[hb1 + ((oct ^ sx) << 3)];
                const short8 a = wf2[(wv * 8 + ks) * 64 + lane];
                acc[0] = __builtin_amdgcn_mfma_f32_16x16x32_bf16(a, bb0, acc[0], 0, 0, 0);
                acc[1] = __builtin_amdgcn_mfma_f32_16x16x32_bf16(a, bb1, acc[1], 0, 0, 0);
            }
            const int out0 = wv * 16 + row0;
            #pragma unroll
            for (int ps = 0; ps < 2; ++ps) {
                f32x4 a4 = acc[ps];
                a4.x = leaky(a4.x); a4.y = leaky(a4.y);
                a4.z = leaky(a4.z); a4.w = leaky(a4.w);
                h2f[ps] = a4;
                uint2 pk;
                pk.x = pkbf(a4.x, a4.y);
                pk.y = pkbf(a4.z, a4.w);
                *(uint2*)&h2s[(ps * 16 + n0) * 128 + (((out0 >> 3) ^ sx) << 3) + (out0 & 7)] = pk;
            }
        }
        __syncthreads();   // B3: h2s ready (also orders L2 h1s-reads before wbuf writes)

        // ---- layer 3: wave = (o3s, ps3) chunk; + L4 partial logits in registers ----
        {
            f32x4 acc = bv3;
            const int cb = (ps3 * 16 + n0) * 128;
            #pragma unroll
            for (int ks = 0; ks < 4; ++ks) {
                const int oct = ks * 4 + qi;
                const short8 bbv = *(const short8*)&h2s[cb + ((oct ^ sx) << 3)];
                const short8 a = wf3[(o3s * 4 + ks) * 64 + lane];
                acc = __builtin_amdgcn_mfma_f32_16x16x32_bf16(a, bbv, acc, 0, 0, 0);
            }
            f32x4 m3 = acc;
            m3.x = fmaxf(m3.x, 0.f); m3.y = fmaxf(m3.y, 0.f);
            m3.z = fmaxf(m3.z, 0.f); m3.w = fmaxf(m3.w, 0.f);
            float pl[4];
            #pragma unroll
            for (int q = 0; q < 4; ++q) {
                const f32x4 w4r = *(const f32x4*)&w4[q * 64 + o3s * 16 + row0];
                pl[q] = w4r.x * m3.x + w4r.y * m3.y + w4r.z * m3.z + w4r.w * m3.w;
            }
            #pragma unroll
            for (int q = 0; q < 4; ++q) {
                pl[q] += __shfl_xor(pl[q], 16, 64);
                pl[q] += __shfl_xor(pl[q], 32, 64);
            }
            if (qi == 0) {
                #pragma unroll
                for (int q = 0; q < 4; ++q)
                    wbuf[(o3s * 4 + q) * 32 + ps3 * 16 + n0] = pl[q];
            }
        }
        __syncthreads();   // B4: wbuf ready; all h2s(=ts) reads done -> next build safe

        // ---- accum: 2 exps per lane (head = qh), register FMA into Afr ----
        {
            #pragma unroll
            for (int ps = 0; ps < 2; ++ps) {
                const int pos = ps * 16 + n0;
                float lg = wbuf[(0 * 4 + qh) * 32 + pos] + wbuf[(1 * 4 + qh) * 32 + pos]
                         + wbuf[(2 * 4 + qh) * 32 + pos] + wbuf[(3 * 4 + qh) * 32 + pos] + b4s;
                lg = fmaxf(lg, 0.f);
                const float e = ((pos0 + pos) > 360) ? 0.f : __expf(lg);
                Afr[ps].x += e * h2f[ps].x;
                Afr[ps].y += e * h2f[ps].y;
                Afr[ps].z += e * h2f[ps].z;
                Afr[ps].w += e * h2f[ps].w;
                Ss += e;
            }
        }
        // no trailing barrier: accum reads wbuf(=h1s head); next-tile h1s writes follow B1+L1
    }

    // combine possubs then reduce over n0 via shfl butterfly
    f32x4 At;
    At.x = Afr[0].x + Afr[1].x; At.y = Afr[0].y + Afr[1].y;
    At.z = Afr[0].z + Afr[1].z; At.w = Afr[0].w + Afr[1].w;
    #pragma unroll
    for (int bit = 1; bit < 16; bit <<= 1) {
        At.x += __shfl_xor(At.x, bit, 64);
        At.y += __shfl_xor(At.y, bit, 64);
        At.z += __shfl_xor(At.z, bit, 64);
        At.w += __shfl_xor(At.w, bit, 64);
        Ss += __shfl_xor(Ss, bit, 64);
    }
    if (n0 == 0) {
        const int pbA = (s * 512 + bb) * 128 + wv * 16 + row0;
        partA[pbA]     = At.x;
        partA[pbA + 1] = At.y;
        partA[pbA + 2] = At.z;
        partA[pbA + 3] = At.w;
        if (qi == 0 && (wv & 1) == 0) partS[(s * 512 + bb) * 4 + qh] = Ss;
    }
}

template <int NS>
__global__ void merge_out(const float* __restrict__ partA, const float* __restrict__ partS,
                          float* __restrict__ out) {
    const int idx = blockIdx.x * 256 + threadIdx.x;
    if (idx >= 512 * 128) return;
    const int bb = idx >> 7, ch = idx & 127;
    const int q = ch >> 5;
    float Sf = 0.f, Af = 0.f;
    #pragma unroll
    for (int s = 0; s < NS; ++s) {
        Af += partA[(s * 512 + bb) * 128 + ch];
        Sf += partS[(s * 512 + bb) * 4 + q];
    }
    out[idx] = Af / Sf;
}

// ---------------- f32 scalar fallback (known-correct, ws-free) ----------------
__global__ __launch_bounds__(256, 2) void fallback_fused(
    const float* __restrict__ x,
    const float* __restrict__ w1, const float* __restrict__ b1,
    const float* __restrict__ w2, const float* __restrict__ b2,
    const float* __restrict__ w3, const float* __restrict__ b3,
    const float* __restrict__ w4, const float* __restrict__ b4,
    float* __restrict__ out)
{
    __shared__ float smf[14644];
    float* const xp  = smf;
    float* const ts  = smf + 308;
    float* const h1s = smf + 8500;
    float* const h2s = smf + 12596;
    float* const m3s = ts;
    float* const lgs = ts + 1024;

    const int tid = threadIdx.x;
    const int b   = blockIdx.x;
    for (int j = tid; j < 308; j += 256) {
        float v = 0.f;
        const int src = j - 2;
        if (src >= 0 && src < 300) v = x[b * 300 + src];
        xp[j] = v;
    }
    __syncthreads();
    const int q = tid >> 5, dd = tid & 31;
    float M = -1e30f, S = 0.f, A = 0.f;
    for (int tile = 0; tile < 23; ++tile) {
        const int pos0 = tile * 16;
        {
            const int p = tid & 15, kk0 = tid >> 4;
            const int pos = pos0 + p;
            const bool valid = (pos < 361);
            const int hh = valid ? (pos / 19) : 0;
            const int ww = valid ? (pos - hh * 19) : 0;
            #pragma unroll
            for (int i = 0; i < 16; ++i) {
                const int kk = kk0 + (i << 4);
                const int i1 = kk >> 4, j1 = kk & 15;
                float di = 0.f, ndi = 0.f;
                if (valid) {
                    const float u = xp[j1 * 19 + ww];
                    const float v = xp[i1 * 19 + hh];
                    di = u - v; ndi = di / (u + v + 1e-5f);
                }
                ts[(kk << 5) + p] = di;
                ts[(kk << 5) + 16 + p] = ndi;
            }
        }
        __syncthreads();
        {
            const int o = tid;
            float acc[16];
            const float bias = b1[o];
            #pragma unroll
            for (int p = 0; p < 16; ++p) acc[p] = bias;
            for (int k = 0; k < 512; ++k) {
                const float wv = w1[o * 512 + k];
                #pragma unroll
                for (int p = 0; p < 16; ++p) acc[p] += wv * ts[(k << 4) + p];
            }
            #pragma unroll
            for (int p = 0; p < 16; ++p) h1s[(o << 4) + p] = (acc[p] >= 0.f) ? acc[p] : 0.01f * acc[p];
        }
        __syncthreads();
        {
            const int o2 = tid & 127, pb = (tid >> 7) << 3;
            float acc[8];
            const float bias = b2[o2];
            #pragma unroll
            for (int j = 0; j < 8; ++j) acc[j] = bias;
            for (int k = 0; k < 256; ++k) {
                const float wv = w2[o2 * 256 + k];
                #pragma unroll
                for (int j = 0; j < 8; ++j) acc[j] += wv * h1s[(k << 4) + pb + j];
            }
            #pragma unroll
            for (int j = 0; j < 8; ++j) h2s[(o2 << 4) + pb + j] = (acc[j] >= 0.f) ? acc[j] : 0.01f * acc[j];
        }
        __syncthreads();
        {
            const int o3 = tid & 63, pb = (tid >> 6) << 2;
            float acc[4];
            const float bias = b3[o3];
            #pragma unroll
            for (int j = 0; j < 4; ++j) acc[j] = bias;
            for (int k = 0; k < 128; ++k) {
                const float wv = w3[o3 * 128 + k];
                #pragma unroll
                for (int j = 0; j < 4; ++j) acc[j] += wv * h2s[(k << 4) + pb + j];
            }
            #pragma unroll
            for (int j = 0; j < 4; ++j) m3s[(o3 << 4) + pb + j] = fmaxf(acc[j], 0.f);
        }
        __syncthreads();
        if (tid < 64) {
            const int o4 = tid >> 4, p = tid & 15;
            float a = b4[o4];
            for (int k = 0; k < 64; ++k) a += w4[o4 * 64 + k] * m3s[(k << 4) + p];
            a = fmaxf(a, 0.f);
            if (pos0 + p >= 361) a = -1e30f;
            lgs[(o4 << 4) + p] = a;
        }
        __syncthreads();
        if (tid < 128) {
            float l[16];
            #pragma unroll
            for (int p = 0; p < 16; ++p) l[p] = lgs[(q << 4) + p];
            float tmax = l[0];
            #pragma unroll
            for (int p = 1; p < 16; ++p) tmax = fmaxf(tmax, l[p]);
            const float newM = fmaxf(M, tmax);
            const float alpha = __expf(M - newM);
            float ssum = 0.f, asum = 0.f;
            #pragma unroll
            for (int p = 0; p < 16; ++p) {
                const float e = __expf(l[p] - newM);
                ssum += e;
                asum += e * h2s[(((q << 5) + dd) << 4) + p];
            }
            S = S * alpha + ssum; A = A * alpha + asum; M = newM;
        }
        __syncthreads();
    }
    if (tid < 128) out[(b << 7) + tid] = A / S;
}

extern "C" void kernel_launch(void* const* d_in, const int* in_sizes, int n_in,
                              void* d_out, int out_size, void* d_ws, size_t ws_size,
                              hipStream_t stream) {
    const float* x  = (const float*)d_in[0];
    const float* w1 = (const float*)d_in[1];
    const float* b1 = (const float*)d_in[2];
    const float* w2 = (const float*)d_in[3];
    const float* b2 = (const float*)d_in[4];
    const float* w3 = (const float*)d_in[5];
    const float* b3 = (const float*)d_in[6];
    const float* w4 = (const float*)d_in[7];
    const float* b4 = (const float*)d_in[8];
    float* out = (float*)d_out;

    const size_t wbytes = (size_t)WS_W_USHORTS * sizeof(ushort_t);
    ushort_t* ws = (ushort_t*)d_ws;
    const int packBlocks = (WS_W_USHORTS + 255) / 256;

    const size_t need4 = wbytes + (size_t)4 * 512 * 132 * sizeof(float);
    const size_t need2 = wbytes + (size_t)2 * 512 * 132 * sizeof(float);
    const size_t need1 = wbytes + (size_t)1 * 512 * 132 * sizeof(float);

    if (ws_size >= need4) {
        float* pA = (float*)((char*)d_ws + wbytes);
        float* pS = pA + (size_t)4 * 512 * 128;
        pack_weights<<<packBlocks, 256, 0, stream>>>(w1, w2, w3, ws);
        fused_mfma<4><<<2048, 512, 0, stream>>>(x, ws, b1, b2, b3, b4, w4, pA, pS);
        merge_out<4><<<256, 256, 0, stream>>>(pA, pS, out);
    } else if (ws_size >= need2) {
        float* pA = (float*)((char*)d_ws + wbytes);
        float* pS = pA + (size_t)2 * 512 * 128;
        pack_weights<<<packBlocks, 256, 0, stream>>>(w1, w2, w3, ws);
        fused_mfma<2><<<1024, 512, 0, stream>>>(x, ws, b1, b2, b3, b4, w4, pA, pS);
        merge_out<2><<<256, 256, 0, stream>>>(pA, pS, out);
    } else if (ws_size >= need1) {
        float* pA = (float*)((char*)d_ws + wbytes);
        float* pS = pA + (size_t)1 * 512 * 128;
        pack_weights<<<packBlocks, 256, 0, stream>>>(w1, w2, w3, ws);
        fused_mfma<1><<<512, 512, 0, stream>>>(x, ws, b1, b2, b3, b4, w4, pA, pS);
        merge_out<1><<<256, 256, 0, stream>>>(pA, pS, out);
    } else {
        fallback_fused<<<512, 256, 0, stream>>>(x, w1, b1, w2, b2, w3, b3, w4, b4, out);
    }
}